// Round 5
// baseline (213.066 us; speedup 1.0000x reference)
//
#include <hip/hip_runtime.h>
#include <hip/hip_bf16.h>

#define TEMP_INV 14.285714285714286f   // 1/0.07
#define FSCALE 16.0f                   // fp8 pre-scale per operand
#define T1S (TEMP_INV / 256.0f)        // val coefficient (val = 256*sim)

typedef __attribute__((ext_vector_type(4))) float f32x4;

#define ASYNC_COPY16(gp, lp)                                                  \
  __builtin_amdgcn_global_load_lds(                                           \
      (__attribute__((address_space(1))) const void*)(gp),                    \
      (__attribute__((address_space(3))) void*)(lp), 16, 0, 0)

// ---- row L2-normalize -> fp8 e4m3 (x16 scale), labels/histogram, zero stats
// one wave per row; D == 512 (8 floats/lane)
__global__ __launch_bounds__(256) void norm_label_k(const float* __restrict__ feat,
                                                    uchar* __restrict__ fq,
                                                    const int* __restrict__ labels,
                                                    const int* __restrict__ kptr,
                                                    int* __restrict__ glab,
                                                    int* __restrict__ cnt,
                                                    float* __restrict__ zbuf,
                                                    int N, int D) {
  const int zi = blockIdx.x * 256 + threadIdx.x;
  if (zi < 2 * N) zbuf[zi] = 0.f;

  const int row = (blockIdx.x * 256 + threadIdx.x) >> 6;
  const int lane = threadIdx.x & 63;
  if (row < N) {
    const float4* fr = (const float4*)(feat + (size_t)row * D);
    float4 v0 = fr[lane * 2];
    float4 v1 = fr[lane * 2 + 1];
    float ss = v0.x * v0.x + v0.y * v0.y + v0.z * v0.z + v0.w * v0.w +
               v1.x * v1.x + v1.y * v1.y + v1.z * v1.z + v1.w * v1.w;
    #pragma unroll
    for (int off = 32; off; off >>= 1) ss += __shfl_xor(ss, off, 64);
    const float inv = FSCALE / fmaxf(sqrtf(ss), 1e-12f);
    int w0 = 0, w1 = 0;
    w0 = __builtin_amdgcn_cvt_pk_fp8_f32(v0.x * inv, v0.y * inv, w0, false);
    w0 = __builtin_amdgcn_cvt_pk_fp8_f32(v0.z * inv, v0.w * inv, w0, true);
    w1 = __builtin_amdgcn_cvt_pk_fp8_f32(v1.x * inv, v1.y * inv, w1, false);
    w1 = __builtin_amdgcn_cvt_pk_fp8_f32(v1.z * inv, v1.w * inv, w1, true);
    uint2 o; o.x = (uint)w0; o.y = (uint)w1;
    *(uint2*)(fq + (size_t)row * D + lane * 8) = o;
  }
  if (blockIdx.x == 0) {
    const int k = *kptr;
    const int B = N / k;
    __shared__ int h[64];
    const int t = threadIdx.x;
    if (t < 64) h[t] = 0;
    __syncthreads();
    for (int b = t; b < B; b += 256) {
      int lb = labels[(size_t)b * k];
      if (lb >= 0 && lb < 64) atomicAdd(&h[lb], 1);
    }
    __syncthreads();
    if (t < 64) cnt[t] = h[t];
    for (int i = t; i < N; i += 256) glab[i] = labels[(size_t)(i / k) * k];
  }
}

// ---- fused fp8 GEMM + masked-softmax-stats, upper-triangle blocks only ----
// 128x128 tile, BK=128 fp8 bytes (16 KB/tile, 32 KB LDS), 4 waves, 4x4 frags
// of 16x16x32 fp8 MFMA. 16B-chunk XOR swizzle (chunk ^ (row>>1)&7) applied at
// the DMA source; ds_read_b64 lands 2-way on banks (free).
// Off-diagonal blocks (bi<bj) also emit column stats (sim symmetric).
__global__ __launch_bounds__(256, 6) void gemm_k(const uchar* __restrict__ fq,
                                                 const int* __restrict__ glab,
                                                 float* __restrict__ rowS,
                                                 float* __restrict__ rowP,
                                                 int N, int D) {
  __shared__ uchar As[128 * 128];
  __shared__ uchar Bs[128 * 128];
  __shared__ int rlb[128], clb[128];
  const int t = threadIdx.x;
  const int lane = t & 63;
  const int wid = t >> 6;
  const int wrow = wid >> 1, wcol = wid & 1;
  const int quad = lane >> 4, l15 = lane & 15;

  // decode upper-triangle block (bi, bj), bj >= bi
  const int nb = N / 128;
  int idx = blockIdx.x, bi = 0;
  while (idx >= nb - bi) { idx -= nb - bi; bi++; }
  const int bj = bi + idx;
  const int i0 = bi * 128, j0 = bj * 128;
  const bool diagblk = (bi == bj);

  if (t < 128) {
    rlb[t] = glab[i0 + t];
    clb[t] = glab[j0 + t];
  }

  f32x4 acc[4][4];
  #pragma unroll
  for (int mi = 0; mi < 4; mi++)
    #pragma unroll
    for (int ni = 0; ni < 4; ni++) {
      f32x4 z = {0.f, 0.f, 0.f, 0.f};
      acc[mi][ni] = z;
    }

  // staging: wave w stages 64 rows (8 DMAs x 8 rows) of A (w<2) or B (w>=2)
  uchar* sb = (wid < 2) ? As : Bs;
  const int rbase = (wid & 1) * 64;
  const int rowstart = ((wid < 2) ? i0 : j0) + rbase;
  const int lrow = lane >> 3;  // 0..7: row within one DMA group
  const int lch = lane & 7;    // 16B LDS chunk written by this lane

  const int h8 = (quad & 1) * 8;   // byte offset within 16B chunk
  const int gq = quad >> 1;        // chunk parity from quad

  for (int kb = 0; kb < D; kb += 128) {   // D bytes; 4 iterations
    __syncthreads();
    #pragma unroll
    for (int d = 0; d < 8; d++) {
      const int rl = d * 8 + lrow;
      const int cg = lch ^ ((rl >> 1) & 7);   // swizzled source chunk
      ASYNC_COPY16(fq + (size_t)(rowstart + rl) * D + kb + cg * 16,
                   sb + (rbase + d * 8) * 128);
    }
    __syncthreads();
    #pragma unroll
    for (int s = 0; s < 4; s++) {
      const int gc = 2 * s + gq;              // logical 16B chunk (k bytes /16)
      long a[4], b[4];
      #pragma unroll
      for (int mi = 0; mi < 4; mi++) {
        const int r = wrow * 64 + mi * 16 + l15;
        a[mi] = *(const long*)&As[r * 128 + ((gc ^ ((r >> 1) & 7)) << 4) + h8];
      }
      #pragma unroll
      for (int ni = 0; ni < 4; ni++) {
        const int r = wcol * 64 + ni * 16 + l15;
        b[ni] = *(const long*)&Bs[r * 128 + ((gc ^ ((r >> 1) & 7)) << 4) + h8];
      }
      #pragma unroll
      for (int mi = 0; mi < 4; mi++)
        #pragma unroll
        for (int ni = 0; ni < 4; ni++)
          acc[mi][ni] = __builtin_amdgcn_mfma_f32_16x16x32_fp8_fp8(a[mi], b[ni], acc[mi][ni], 0, 0, 0);
    }
  }

  // ---- epilogue ----
  const int colbase = j0 + wcol * 64 + l15;
  int clab[4];
  #pragma unroll
  for (int ni = 0; ni < 4; ni++) clab[ni] = clb[wcol * 64 + ni * 16 + l15];

  float colE[4] = {0.f, 0.f, 0.f, 0.f};
  float colP[4] = {0.f, 0.f, 0.f, 0.f};

  if (!diagblk) {
    #pragma unroll
    for (int mi = 0; mi < 4; mi++) {
      const int lrw = wrow * 64 + mi * 16 + quad * 4;
      #pragma unroll
      for (int r = 0; r < 4; r++) {
        const int row = i0 + lrw + r;
        const int rlab = rlb[lrw + r];
        float Ssum = 0.f, Psum = 0.f;
        #pragma unroll
        for (int ni = 0; ni < 4; ni++) {
          const float val = acc[mi][ni][r];
          const float lg = fmaf(val, T1S, -TEMP_INV);  // (sim-1)/T
          const float e = __expf(lg);
          const float pm = (rlab == clab[ni]) ? lg : 0.f;
          Ssum += e; Psum += pm;
          colE[ni] += e; colP[ni] += pm;
        }
        #pragma unroll
        for (int off = 8; off; off >>= 1) {
          Ssum += __shfl_xor(Ssum, off, 64);
          Psum += __shfl_xor(Psum, off, 64);
        }
        if (l15 == 0) {
          atomicAdd(&rowS[row], Ssum);
          atomicAdd(&rowP[row], Psum);
        }
      }
    }
    #pragma unroll
    for (int ni = 0; ni < 4; ni++) {
      float e = colE[ni];
      float p = colP[ni];
      e += __shfl_xor(e, 16, 64);
      e += __shfl_xor(e, 32, 64);
      p += __shfl_xor(p, 16, 64);
      p += __shfl_xor(p, 32, 64);
      if (quad == 0) {
        atomicAdd(&rowS[colbase + ni * 16], e);
        atomicAdd(&rowP[colbase + ni * 16], p);
      }
    }
  } else {
    #pragma unroll
    for (int mi = 0; mi < 4; mi++) {
      const int lrw = wrow * 64 + mi * 16 + quad * 4;
      #pragma unroll
      for (int r = 0; r < 4; r++) {
        const int row = i0 + lrw + r;
        const int rlab = rlb[lrw + r];
        float Ssum = 0.f, Psum = 0.f;
        #pragma unroll
        for (int ni = 0; ni < 4; ni++) {
          const int col = colbase + ni * 16;
          const float val = acc[mi][ni][r];
          const float lg = fmaf(val, T1S, -TEMP_INV);
          const bool diag = (row == col);
          const float e = diag ? 0.f : __expf(lg);
          const float pm = (!diag && rlab == clab[ni]) ? lg : 0.f;
          Ssum += e; Psum += pm;
        }
        #pragma unroll
        for (int off = 8; off; off >>= 1) {
          Ssum += __shfl_xor(Ssum, off, 64);
          Psum += __shfl_xor(Psum, off, 64);
        }
        if (l15 == 0) {
          atomicAdd(&rowS[row], Ssum);
          atomicAdd(&rowP[row], Psum);
        }
      }
    }
  }
}

// ---------------- final loss reduction ----------------
__global__ __launch_bounds__(1024) void loss_k(const float* __restrict__ rowS,
                                               const float* __restrict__ rowP,
                                               const int* __restrict__ glab,
                                               const int* __restrict__ cnt,
                                               const int* __restrict__ kptr,
                                               float* __restrict__ out, int N) {
  const int k = *kptr;
  const int t = threadIdx.x;
  float lsum = 0.f, vsum = 0.f;
  for (int i = t; i < N; i += 1024) {
    const int np = cnt[glab[i]] * k - 1;
    if (np > 0) {
      const float S = rowS[i] + 1e-8f;
      const float P = rowP[i];
      lsum += -(P - (float)np * logf(S)) / (float)np;
      vsum += 1.f;
    }
  }
  #pragma unroll
  for (int off = 32; off; off >>= 1) {
    lsum += __shfl_xor(lsum, off, 64);
    vsum += __shfl_xor(vsum, off, 64);
  }
  __shared__ float sl[16], sv[16];
  if ((t & 63) == 0) { sl[t >> 6] = lsum; sv[t >> 6] = vsum; }
  __syncthreads();
  if (t == 0) {
    float L = 0.f, V = 0.f;
    #pragma unroll
    for (int i = 0; i < 16; i++) { L += sl[i]; V += sv[i]; }
    out[0] = L / fmaxf(V, 1.f);
  }
}

extern "C" void kernel_launch(void* const* d_in, const int* in_sizes, int n_in,
                              void* d_out, int out_size, void* d_ws, size_t ws_size,
                              hipStream_t stream) {
  const float* feat = (const float*)d_in[0];
  const int* labels = (const int*)d_in[1];
  const int* kptr   = (const int*)d_in[2];
  const int N = in_sizes[1];
  const int D = in_sizes[0] / N;  // 512

  char* ws = (char*)d_ws;
  uchar* fq = (uchar*)ws;
  size_t off = (size_t)N * D;  // fp8: 1 byte/elem
  float* rowS = (float*)(ws + off); off += (size_t)N * sizeof(float);
  float* rowP = (float*)(ws + off); off += (size_t)N * sizeof(float);
  int* glab   = (int*)(ws + off);   off += (size_t)N * sizeof(int);
  int* cnt    = (int*)(ws + off);   off += 64 * sizeof(int);

  norm_label_k<<<(N + 3) / 4, 256, 0, stream>>>(feat, fq, labels, kptr, glab, cnt,
                                                rowS, N, D);
  const int nb = N / 128;
  gemm_k<<<nb * (nb + 1) / 2, 256, 0, stream>>>(fq, glab, rowS, rowP, N, D);
  loss_k<<<1, 1024, 0, stream>>>(rowS, rowP, glab, cnt, kptr, (float*)d_out, N);
}

// Round 6
// 161.479 us; speedup vs baseline: 1.3195x; 1.3195x over previous
//
#include <hip/hip_runtime.h>
#include <hip/hip_bf16.h>

#define TEMP_INV 14.285714285714286f  // 1/0.07

typedef __attribute__((ext_vector_type(8))) short bf16x8;
typedef __attribute__((ext_vector_type(4))) float f32x4;

#define ASYNC_COPY16(gp, lp)                                                  \
  __builtin_amdgcn_global_load_lds(                                           \
      (__attribute__((address_space(1))) const void*)(gp),                    \
      (__attribute__((address_space(3))) void*)(lp), 16, 0, 0)

// ---- row L2-normalize -> bf16, labels/histogram + accumulator zeroing (blk 0)
__global__ __launch_bounds__(256) void norm_label_k(const float* __restrict__ feat,
                                                    ushort* __restrict__ fbf,
                                                    const int* __restrict__ labels,
                                                    const int* __restrict__ kptr,
                                                    int* __restrict__ glab,
                                                    int* __restrict__ cnt,
                                                    float* __restrict__ gacc,
                                                    int* __restrict__ dcnt,
                                                    int N, int D) {
  const int row = (blockIdx.x * 256 + threadIdx.x) >> 6;
  const int lane = threadIdx.x & 63;
  if (row < N) {
    const float4* fr = (const float4*)(feat + (size_t)row * D);
    float4 v0 = fr[lane];
    float4 v1 = fr[lane + 64];
    float ss = v0.x * v0.x + v0.y * v0.y + v0.z * v0.z + v0.w * v0.w +
               v1.x * v1.x + v1.y * v1.y + v1.z * v1.z + v1.w * v1.w;
    #pragma unroll
    for (int off = 32; off; off >>= 1) ss += __shfl_xor(ss, off, 64);
    const float inv = 1.0f / fmaxf(sqrtf(ss), 1e-12f);
    float x0[4] = {v0.x, v0.y, v0.z, v0.w};
    float x1[4] = {v1.x, v1.y, v1.z, v1.w};
    ushort o0[4], o1[4];
    #pragma unroll
    for (int i = 0; i < 4; i++) {
      __hip_bfloat16 h0 = __float2bfloat16(x0[i] * inv);
      __hip_bfloat16 h1 = __float2bfloat16(x1[i] * inv);
      o0[i] = *(ushort*)&h0;
      o1[i] = *(ushort*)&h1;
    }
    *(uint2*)(fbf + (size_t)row * D + lane * 4)       = *(uint2*)o0;
    *(uint2*)(fbf + (size_t)row * D + 256 + lane * 4) = *(uint2*)o1;
  }
  if (blockIdx.x == 0) {
    const int k = *kptr;
    const int B = N / k;
    __shared__ int h[64];
    const int t = threadIdx.x;
    if (t < 2) gacc[t] = 0.f;
    if (t == 2) *dcnt = 0;
    if (t < 64) h[t] = 0;
    __syncthreads();
    for (int b = t; b < B; b += 256) {
      int lb = labels[(size_t)b * k];
      if (lb >= 0 && lb < 64) atomicAdd(&h[lb], 1);
    }
    __syncthreads();
    if (t < 64) cnt[t] = h[t];
    for (int i = t; i < N; i += 256) glab[i] = labels[(size_t)(i / k) * k];
  }
}

// ---- fused GEMM + masked-softmax-stats, upper-triangle blocks only ----
// 128x128 tile, BK=64 (32 KB LDS), 4 waves, 4x4 frags of 16x16x32 bf16 MFMA.
// Chunk-XOR swizzle (chunk ^ row&7) at DMA source; ds_read_b128 2-way (free).
// NO global atomics: per-block partials (rowS/rowP/colS/colP) are combined in
// (reused tile) LDS and written as one coalesced 2 KB record per block.
__global__ __launch_bounds__(256, 4) void gemm_k(const ushort* __restrict__ fbf,
                                                 const int* __restrict__ glab,
                                                 float* __restrict__ part,
                                                 int N, int D) {
  __shared__ ushort As[128 * 64];
  __shared__ ushort Bs[128 * 64];
  const int t = threadIdx.x;
  const int lane = t & 63;
  const int wid = t >> 6;
  const int wrow = wid >> 1, wcol = wid & 1;
  const int quad = lane >> 4, l15 = lane & 15;

  // XCD-band remap: give each XCD a contiguous band of the triangle
  const int nb = N / 128;
  const int total = nb * (nb + 1) / 2;
  int gidx = blockIdx.x;
  if ((total & 7) == 0) {
    const int per = total >> 3;
    gidx = (blockIdx.x & 7) * per + (blockIdx.x >> 3);
  }
  // decode upper-triangle block (bi, bj), bj >= bi
  int idx = gidx, bi = 0;
  while (idx >= nb - bi) { idx -= nb - bi; bi++; }
  const int bj = bi + idx;
  const int i0 = bi * 128, j0 = bj * 128;
  const bool diagblk = (bi == bj);

  f32x4 acc[4][4];
  #pragma unroll
  for (int mi = 0; mi < 4; mi++)
    #pragma unroll
    for (int ni = 0; ni < 4; ni++) {
      f32x4 z = {0.f, 0.f, 0.f, 0.f};
      acc[mi][ni] = z;
    }

  // staging: wave w stages 64 rows (8 DMAs x 8 rows) of A (w<2) or B (w>=2)
  ushort* sb = (wid < 2) ? As : Bs;
  const int rbase = (wid & 1) * 64;
  const int rowstart = ((wid < 2) ? i0 : j0) + rbase;
  const int lrow = lane >> 3;  // 0..7 row within DMA group
  const int lch = lane & 7;    // LDS 16B chunk written by this lane

  for (int kb = 0; kb < D; kb += 64) {
    __syncthreads();
    #pragma unroll
    for (int i = 0; i < 8; i++) {
      const int rl = 8 * i + lrow;
      const int cg = lch ^ (rl & 7);  // swizzled source chunk
      ASYNC_COPY16(fbf + (size_t)(rowstart + rl) * D + kb + cg * 8,
                   sb + (rbase + 8 * i) * 64);
    }
    __syncthreads();
    #pragma unroll
    for (int s = 0; s < 2; s++) {
      const int ch = s * 4 + quad;  // logical 16B chunk within 128B row
      bf16x8 a[4], b[4];
      #pragma unroll
      for (int mi = 0; mi < 4; mi++) {
        const int r = wrow * 64 + mi * 16 + l15;
        a[mi] = *(const bf16x8*)&As[r * 64 + ((ch ^ (r & 7)) * 8)];
      }
      #pragma unroll
      for (int ni = 0; ni < 4; ni++) {
        const int r = wcol * 64 + ni * 16 + l15;
        b[ni] = *(const bf16x8*)&Bs[r * 64 + ((ch ^ (r & 7)) * 8)];
      }
      #pragma unroll
      for (int mi = 0; mi < 4; mi++)
        #pragma unroll
        for (int ni = 0; ni < 4; ni++)
          acc[mi][ni] = __builtin_amdgcn_mfma_f32_16x16x32_bf16(a[mi], b[ni], acc[mi][ni], 0, 0, 0);
    }
  }

  // ---- epilogue: stats into reused LDS, then one coalesced store ----
  __syncthreads();                 // all tile reads done; As reusable
  float* sf = (float*)As;          // [0:256) rowS(2x128) [256:512) rowP
                                   // [512:768) colS(2x128) [768:1024) colP
  const int colbase = j0 + wcol * 64 + l15;
  int clab[4];
  #pragma unroll
  for (int ni = 0; ni < 4; ni++) clab[ni] = glab[colbase + ni * 16];

  float colE[4] = {0.f, 0.f, 0.f, 0.f};
  float colP[4] = {0.f, 0.f, 0.f, 0.f};

  #pragma unroll
  for (int mi = 0; mi < 4; mi++) {
    const int lrw = wrow * 64 + mi * 16 + quad * 4;
    #pragma unroll
    for (int r = 0; r < 4; r++) {
      const int row = i0 + lrw + r;
      const int rlab = glab[row];
      float Ssum = 0.f, Psum = 0.f;
      #pragma unroll
      for (int ni = 0; ni < 4; ni++) {
        const int col = colbase + ni * 16;
        const float val = acc[mi][ni][r];
        const float lg = fmaf(val, TEMP_INV, -TEMP_INV);  // (sim - 1)/T
        const bool diag = diagblk && (row == col);
        const float e = diag ? 0.f : __expf(lg);
        const float pm = (!diag && rlab == clab[ni]) ? lg : 0.f;
        Ssum += e; Psum += pm;
        colE[ni] += e; colP[ni] += pm;
      }
      #pragma unroll
      for (int off = 8; off; off >>= 1) {
        Ssum += __shfl_xor(Ssum, off, 64);
        Psum += __shfl_xor(Psum, off, 64);
      }
      if (l15 == 0) {
        sf[wcol * 128 + lrw + r]       = Ssum;
        sf[256 + wcol * 128 + lrw + r] = Psum;
      }
    }
  }
  if (!diagblk) {
    #pragma unroll
    for (int ni = 0; ni < 4; ni++) {
      float e = colE[ni];
      float p = colP[ni];
      e += __shfl_xor(e, 16, 64);
      e += __shfl_xor(e, 32, 64);
      p += __shfl_xor(p, 16, 64);
      p += __shfl_xor(p, 32, 64);
      const int lcol = wcol * 64 + ni * 16 + l15;
      if (quad == 0) {
        sf[512 + wrow * 128 + lcol] = e;
        sf[768 + wrow * 128 + lcol] = p;
      }
    }
  }
  __syncthreads();
  float* dst = part + (size_t)gidx * 512;
  if (t < 128) {
    dst[t]       = sf[t] + sf[128 + t];          // rowS
    dst[128 + t] = sf[256 + t] + sf[384 + t];    // rowP
  } else if (!diagblk) {
    const int u = t - 128;
    dst[256 + u] = sf[512 + u] + sf[640 + u];    // colS
    dst[384 + u] = sf[768 + u] + sf[896 + u];    // colP
  }
}

// ---- gather partials -> per-row loss -> global reduce -> finalize ----
// one block per 128-row strip; thread t handles row b*128+t
__global__ __launch_bounds__(128) void reduce_loss_k(const float* __restrict__ part,
                                                     const int* __restrict__ glab,
                                                     const int* __restrict__ cnt,
                                                     const int* __restrict__ kptr,
                                                     float* __restrict__ gacc,
                                                     int* __restrict__ dcnt,
                                                     float* __restrict__ out, int N) {
  const int nb = N / 128;
  const int b = blockIdx.x;
  const int t = threadIdx.x;
  const int i = b * 128 + t;
  float S = 0.f, P = 0.f;
  const int base = b * nb - b * (b - 1) / 2;
  for (int bj = b; bj < nb; bj++) {          // row-side partials
    const float* p = part + (size_t)(base + bj - b) * 512;
    S += p[t];
    P += p[128 + t];
  }
  for (int bi = 0; bi < b; bi++) {           // col-side partials (symmetry)
    const int idx = bi * nb - bi * (bi - 1) / 2 + (b - bi);
    const float* p = part + (size_t)idx * 512;
    S += p[256 + t];
    P += p[384 + t];
  }
  const int k = *kptr;
  const int np = cnt[glab[i]] * k - 1;
  float l = 0.f, v = 0.f;
  if (np > 0) {
    l = -(P - (float)np * logf(S + 1e-8f)) / (float)np;
    v = 1.f;
  }
  #pragma unroll
  for (int off = 32; off; off >>= 1) {
    l += __shfl_xor(l, off, 64);
    v += __shfl_xor(v, off, 64);
  }
  __shared__ float sl[2], sv[2];
  if ((t & 63) == 0) { sl[t >> 6] = l; sv[t >> 6] = v; }
  __syncthreads();
  if (t == 0) {
    atomicAdd(&gacc[0], sl[0] + sl[1]);
    atomicAdd(&gacc[1], sv[0] + sv[1]);
    __threadfence();
    const int prev = atomicAdd(dcnt, 1);
    if (prev == (int)gridDim.x - 1) {
      const float L = atomicAdd(&gacc[0], 0.f);
      const float V = atomicAdd(&gacc[1], 0.f);
      out[0] = L / fmaxf(V, 1.f);
    }
  }
}

extern "C" void kernel_launch(void* const* d_in, const int* in_sizes, int n_in,
                              void* d_out, int out_size, void* d_ws, size_t ws_size,
                              hipStream_t stream) {
  const float* feat = (const float*)d_in[0];
  const int* labels = (const int*)d_in[1];
  const int* kptr   = (const int*)d_in[2];
  const int N = in_sizes[1];
  const int D = in_sizes[0] / N;  // 512

  const int nb = N / 128;
  const int total = nb * (nb + 1) / 2;

  char* ws = (char*)d_ws;
  ushort* fbf = (ushort*)ws;
  size_t off = (size_t)N * D * sizeof(ushort);
  float* part = (float*)(ws + off); off += (size_t)total * 512 * sizeof(float);
  int* glab   = (int*)(ws + off);   off += (size_t)N * sizeof(int);
  int* cnt    = (int*)(ws + off);   off += 64 * sizeof(int);
  float* gacc = (float*)(ws + off); off += 2 * sizeof(float);
  int* dcnt   = (int*)(ws + off);   off += sizeof(int);

  norm_label_k<<<(N + 3) / 4, 256, 0, stream>>>(feat, fbf, labels, kptr, glab, cnt,
                                                gacc, dcnt, N, D);
  gemm_k<<<total, 256, 0, stream>>>(fbf, glab, part, N, D);
  reduce_loss_k<<<nb, 128, 0, stream>>>(part, glab, cnt, kptr, gacc, dcnt,
                                        (float*)d_out, N);
}

// Round 7
// 152.366 us; speedup vs baseline: 1.3984x; 1.0598x over previous
//
#include <hip/hip_runtime.h>
#include <hip/hip_bf16.h>

#define TEMP_INV 14.285714285714286f  // 1/0.07
#define FSCALE 16.0f                  // fp8 pre-scale per operand
#define T1S (TEMP_INV / 256.0f)       // acc = 256*sim -> (sim-1)/T = acc*T1S - TEMP_INV

typedef __attribute__((ext_vector_type(4))) float f32x4;

#define ASYNC_COPY16(gp, lp)                                                  \
  __builtin_amdgcn_global_load_lds(                                           \
      (__attribute__((address_space(1))) const void*)(gp),                    \
      (__attribute__((address_space(3))) void*)(lp), 16, 0, 0)

// ---- row L2-normalize -> fp8 e4m3 (x16), labels/histogram + acc zero (blk 0)
__global__ __launch_bounds__(256) void norm_label_k(const float* __restrict__ feat,
                                                    uchar* __restrict__ fq,
                                                    const int* __restrict__ labels,
                                                    const int* __restrict__ kptr,
                                                    int* __restrict__ glab,
                                                    int* __restrict__ cnt,
                                                    float* __restrict__ gacc,
                                                    int* __restrict__ dcnt,
                                                    int N, int D) {
  const int row = (blockIdx.x * 256 + threadIdx.x) >> 6;
  const int lane = threadIdx.x & 63;
  if (row < N) {
    const float4* fr = (const float4*)(feat + (size_t)row * D);
    float4 v0 = fr[lane * 2];
    float4 v1 = fr[lane * 2 + 1];
    float ss = v0.x * v0.x + v0.y * v0.y + v0.z * v0.z + v0.w * v0.w +
               v1.x * v1.x + v1.y * v1.y + v1.z * v1.z + v1.w * v1.w;
    #pragma unroll
    for (int off = 32; off; off >>= 1) ss += __shfl_xor(ss, off, 64);
    const float inv = FSCALE / fmaxf(sqrtf(ss), 1e-12f);
    int w0 = 0, w1 = 0;
    w0 = __builtin_amdgcn_cvt_pk_fp8_f32(v0.x * inv, v0.y * inv, w0, false);
    w0 = __builtin_amdgcn_cvt_pk_fp8_f32(v0.z * inv, v0.w * inv, w0, true);
    w1 = __builtin_amdgcn_cvt_pk_fp8_f32(v1.x * inv, v1.y * inv, w1, false);
    w1 = __builtin_amdgcn_cvt_pk_fp8_f32(v1.z * inv, v1.w * inv, w1, true);
    uint2 o; o.x = (uint)w0; o.y = (uint)w1;
    *(uint2*)(fq + (size_t)row * D + lane * 8) = o;
  }
  if (blockIdx.x == 0) {
    const int k = *kptr;
    const int B = N / k;
    __shared__ int h[64];
    const int t = threadIdx.x;
    if (t < 2) gacc[t] = 0.f;
    if (t == 2) *dcnt = 0;
    if (t < 64) h[t] = 0;
    __syncthreads();
    for (int b = t; b < B; b += 256) {
      int lb = labels[(size_t)b * k];
      if (lb >= 0 && lb < 64) atomicAdd(&h[lb], 1);
    }
    __syncthreads();
    if (t < 64) cnt[t] = h[t];
    for (int i = t; i < N; i += 256) glab[i] = labels[(size_t)(i / k) * k];
  }
}

// ---- fused fp8 GEMM + masked-softmax-stats, upper-triangle blocks only ----
// 128x128 tile, BK=128 fp8 bytes (row = 128 B, same geometry as r6), 4 waves,
// 4x4 frags of 16x16x32 fp8 MFMA. Chunk-XOR swizzle (c16 ^ row&7) at DMA
// source; fp8 b64 frag reads are 2-way on banks (free).
// NO global atomics: per-block partials written as one coalesced 2 KB record.
__global__ __launch_bounds__(256, 4) void gemm_k(const uchar* __restrict__ fq,
                                                 const int* __restrict__ glab,
                                                 float* __restrict__ part,
                                                 int N, int D) {
  __shared__ uchar As[128 * 128];
  __shared__ uchar Bs[128 * 128];
  const int t = threadIdx.x;
  const int lane = t & 63;
  const int wid = t >> 6;
  const int wrow = wid >> 1, wcol = wid & 1;
  const int quad = lane >> 4, l15 = lane & 15;

  // XCD-band remap: give each XCD a contiguous band of the triangle
  const int nb = N / 128;
  const int total = nb * (nb + 1) / 2;
  int gidx = blockIdx.x;
  if ((total & 7) == 0) {
    const int per = total >> 3;
    gidx = (blockIdx.x & 7) * per + (blockIdx.x >> 3);
  }
  // decode upper-triangle block (bi, bj), bj >= bi
  int idx = gidx, bi = 0;
  while (idx >= nb - bi) { idx -= nb - bi; bi++; }
  const int bj = bi + idx;
  const int i0 = bi * 128, j0 = bj * 128;
  const bool diagblk = (bi == bj);

  f32x4 acc[4][4];
  #pragma unroll
  for (int mi = 0; mi < 4; mi++)
    #pragma unroll
    for (int ni = 0; ni < 4; ni++) {
      f32x4 z = {0.f, 0.f, 0.f, 0.f};
      acc[mi][ni] = z;
    }

  // staging: wave w stages 64 rows (8 DMAs x 8 rows x 128 B) of A or B
  uchar* sb = (wid < 2) ? As : Bs;
  const int rbase = (wid & 1) * 64;
  const int rowstart = ((wid < 2) ? i0 : j0) + rbase;
  const int lrow = lane >> 3;  // 0..7: row within one 8-row DMA group
  const int lch = lane & 7;    // 16B LDS chunk written by this lane

  const int h8 = (quad & 1) * 8;  // 8B half within 16B chunk
  const int cq = quad >> 1;       // chunk parity from quad

  for (int kb = 0; kb < D; kb += 128) {  // 4 iterations (D=512 bytes)
    __syncthreads();
    #pragma unroll
    for (int i = 0; i < 8; i++) {
      const int rl = 8 * i + lrow;
      const int cg = lch ^ (rl & 7);  // swizzled source chunk
      ASYNC_COPY16(fq + (size_t)(rowstart + rl) * D + kb + cg * 16,
                   sb + (rbase + 8 * i) * 128);
    }
    __syncthreads();
    #pragma unroll
    for (int s = 0; s < 4; s++) {
      const int c16 = s * 2 + cq;  // logical 16B chunk holding this quad's k
      long a[4], b[4];
      #pragma unroll
      for (int mi = 0; mi < 4; mi++) {
        const int r = wrow * 64 + mi * 16 + l15;
        a[mi] = *(const long*)&As[r * 128 + ((c16 ^ (r & 7)) << 4) + h8];
      }
      #pragma unroll
      for (int ni = 0; ni < 4; ni++) {
        const int r = wcol * 64 + ni * 16 + l15;
        b[ni] = *(const long*)&Bs[r * 128 + ((c16 ^ (r & 7)) << 4) + h8];
      }
      #pragma unroll
      for (int mi = 0; mi < 4; mi++)
        #pragma unroll
        for (int ni = 0; ni < 4; ni++)
          acc[mi][ni] = __builtin_amdgcn_mfma_f32_16x16x32_fp8_fp8(a[mi], b[ni], acc[mi][ni], 0, 0, 0);
    }
  }

  // ---- epilogue: stats into reused LDS, then one coalesced store ----
  __syncthreads();                 // all tile reads done; As reusable
  float* sf = (float*)As;          // [0:256) rowS(2x128) [256:512) rowP
                                   // [512:768) colS(2x128) [768:1024) colP
  const int colbase = j0 + wcol * 64 + l15;
  int clab[4];
  #pragma unroll
  for (int ni = 0; ni < 4; ni++) clab[ni] = glab[colbase + ni * 16];

  float colE[4] = {0.f, 0.f, 0.f, 0.f};
  float colP[4] = {0.f, 0.f, 0.f, 0.f};

  #pragma unroll
  for (int mi = 0; mi < 4; mi++) {
    const int lrw = wrow * 64 + mi * 16 + quad * 4;
    #pragma unroll
    for (int r = 0; r < 4; r++) {
      const int row = i0 + lrw + r;
      const int rlab = glab[row];
      float Ssum = 0.f, Psum = 0.f;
      #pragma unroll
      for (int ni = 0; ni < 4; ni++) {
        const int col = colbase + ni * 16;
        const float val = acc[mi][ni][r];
        const float lg = fmaf(val, T1S, -TEMP_INV);  // (sim - 1)/T
        const bool diag = diagblk && (row == col);
        const float e = diag ? 0.f : __expf(lg);
        const float pm = (!diag && rlab == clab[ni]) ? lg : 0.f;
        Ssum += e; Psum += pm;
        colE[ni] += e; colP[ni] += pm;
      }
      #pragma unroll
      for (int off = 8; off; off >>= 1) {
        Ssum += __shfl_xor(Ssum, off, 64);
        Psum += __shfl_xor(Psum, off, 64);
      }
      if (l15 == 0) {
        sf[wcol * 128 + lrw + r]       = Ssum;
        sf[256 + wcol * 128 + lrw + r] = Psum;
      }
    }
  }
  if (!diagblk) {
    #pragma unroll
    for (int ni = 0; ni < 4; ni++) {
      float e = colE[ni];
      float p = colP[ni];
      e += __shfl_xor(e, 16, 64);
      e += __shfl_xor(e, 32, 64);
      p += __shfl_xor(p, 16, 64);
      p += __shfl_xor(p, 32, 64);
      const int lcol = wcol * 64 + ni * 16 + l15;
      if (quad == 0) {
        sf[512 + wrow * 128 + lcol] = e;
        sf[768 + wrow * 128 + lcol] = p;
      }
    }
  }
  __syncthreads();
  float* dst = part + (size_t)gidx * 512;
  if (t < 128) {
    dst[t]       = sf[t] + sf[128 + t];          // rowS
    dst[128 + t] = sf[256 + t] + sf[384 + t];    // rowP
  } else if (!diagblk) {
    const int u = t - 128;
    dst[256 + u] = sf[512 + u] + sf[640 + u];    // colS
    dst[384 + u] = sf[768 + u] + sf[896 + u];    // colP
  }
}

// ---- gather partials -> per-row loss -> global reduce -> finalize ----
__global__ __launch_bounds__(128) void reduce_loss_k(const float* __restrict__ part,
                                                     const int* __restrict__ glab,
                                                     const int* __restrict__ cnt,
                                                     const int* __restrict__ kptr,
                                                     float* __restrict__ gacc,
                                                     int* __restrict__ dcnt,
                                                     float* __restrict__ out, int N) {
  const int nb = N / 128;
  const int b = blockIdx.x;
  const int t = threadIdx.x;
  const int i = b * 128 + t;
  float S = 0.f, P = 0.f;
  const int base = b * nb - b * (b - 1) / 2;
  for (int bj = b; bj < nb; bj++) {          // row-side partials
    const float* p = part + (size_t)(base + bj - b) * 512;
    S += p[t];
    P += p[128 + t];
  }
  for (int bi = 0; bi < b; bi++) {           // col-side partials (symmetry)
    const int idx = bi * nb - bi * (bi - 1) / 2 + (b - bi);
    const float* p = part + (size_t)idx * 512;
    S += p[256 + t];
    P += p[384 + t];
  }
  const int k = *kptr;
  const int np = cnt[glab[i]] * k - 1;
  float l = 0.f, v = 0.f;
  if (np > 0) {
    l = -(P - (float)np * logf(S + 1e-8f)) / (float)np;
    v = 1.f;
  }
  #pragma unroll
  for (int off = 32; off; off >>= 1) {
    l += __shfl_xor(l, off, 64);
    v += __shfl_xor(v, off, 64);
  }
  __shared__ float sl[2], sv[2];
  if ((t & 63) == 0) { sl[t >> 6] = l; sv[t >> 6] = v; }
  __syncthreads();
  if (t == 0) {
    atomicAdd(&gacc[0], sl[0] + sl[1]);
    atomicAdd(&gacc[1], sv[0] + sv[1]);
    __threadfence();
    const int prev = atomicAdd(dcnt, 1);
    if (prev == (int)gridDim.x - 1) {
      const float L = atomicAdd(&gacc[0], 0.f);
      const float V = atomicAdd(&gacc[1], 0.f);
      out[0] = L / fmaxf(V, 1.f);
    }
  }
}

extern "C" void kernel_launch(void* const* d_in, const int* in_sizes, int n_in,
                              void* d_out, int out_size, void* d_ws, size_t ws_size,
                              hipStream_t stream) {
  const float* feat = (const float*)d_in[0];
  const int* labels = (const int*)d_in[1];
  const int* kptr   = (const int*)d_in[2];
  const int N = in_sizes[1];
  const int D = in_sizes[0] / N;  // 512

  const int nb = N / 128;
  const int total = nb * (nb + 1) / 2;

  char* ws = (char*)d_ws;
  uchar* fq = (uchar*)ws;
  size_t off = (size_t)N * D;  // fp8: 1 byte/elem
  float* part = (float*)(ws + off); off += (size_t)total * 512 * sizeof(float);
  int* glab   = (int*)(ws + off);   off += (size_t)N * sizeof(int);
  int* cnt    = (int*)(ws + off);   off += 64 * sizeof(int);
  float* gacc = (float*)(ws + off); off += 2 * sizeof(float);
  int* dcnt   = (int*)(ws + off);   off += sizeof(int);

  norm_label_k<<<(N + 3) / 4, 256, 0, stream>>>(feat, fq, labels, kptr, glab, cnt,
                                                gacc, dcnt, N, D);
  gemm_k<<<total, 256, 0, stream>>>(fq, glab, part, N, D);
  reduce_loss_k<<<nb, 128, 0, stream>>>(part, glab, cnt, kptr, gacc, dcnt,
                                        (float*)d_out, N);
}